// Round 1
// baseline (674.470 us; speedup 1.0000x reference)
//
#include <hip/hip_runtime.h>
#include <math.h>

#define BB 16
#define NN 8192
#define MM 64
#define ROW 85
#define NMS_THR 0.5f
#define IOU_MATCH_T 0.5f
#define EPS_F 1e-7f
#define NT 256

// Kernel 1: per-prediction boxes + masked score keys.
// key = valid ? score : -inf, valid = (obj >= 0) && (max IoU vs GT >= 0.5)
__global__ void prep_kernel(const float* __restrict__ outp,
                            const float* __restrict__ lab,
                            float4* __restrict__ boxes,
                            float* __restrict__ keys) {
    __shared__ float4 gbox[MM];
    __shared__ float garea[MM];
    const int b = blockIdx.x;
    const int tid = threadIdx.x;
    if (tid < MM) {
        const float* lr = lab + ((size_t)b * MM + tid) * 5;
        float cx = lr[1], cy = lr[2], w = lr[3], h = lr[4];
        // xywh2xyxy -> clip(0,1) -> *640 (same op order as reference)
        float x1 = fminf(fmaxf(cx - w * 0.5f, 0.f), 1.f) * 640.f;
        float y1 = fminf(fmaxf(cy - h * 0.5f, 0.f), 1.f) * 640.f;
        float x2 = fminf(fmaxf(cx + w * 0.5f, 0.f), 1.f) * 640.f;
        float y2 = fminf(fmaxf(cy + h * 0.5f, 0.f), 1.f) * 640.f;
        gbox[tid] = make_float4(x1, y1, x2, y2);
        garea[tid] = (x2 - x1) * (y2 - y1);
    }
    __syncthreads();
    const int n = blockIdx.y * NT + tid;
    const float* row = outp + ((size_t)b * NN + n) * ROW;
    float cx = row[0], cy = row[1], w = row[2], h = row[3];
    float obj = row[4], c0 = row[5];
    float px1 = cx - w * 0.5f, py1 = cy - h * 0.5f;
    float px2 = cx + w * 0.5f, py2 = cy + h * 0.5f;
    float pa = (px2 - px1) * (py2 - py1);
    bool match = false;
    #pragma unroll 8
    for (int m = 0; m < MM; ++m) {
        float4 g = gbox[m];
        float iw = fmaxf(fminf(px2, g.z) - fmaxf(px1, g.x), 0.f);
        float ih = fmaxf(fminf(py2, g.w) - fmaxf(py1, g.y), 0.f);
        float inter = iw * ih;
        float iou = inter / (garea[m] + pa - inter);   // no EPS (matches box_iou)
        match = match || (iou >= IOU_MATCH_T);
    }
    bool valid = (obj >= 0.0f) && match;
    size_t bn = (size_t)b * NN + n;
    boxes[bn] = make_float4(px1, py1, px2, py2);
    keys[bn] = valid ? (c0 * obj) : -INFINITY;
}

// Kernel 2: per-image greedy NMS by iterative max-selection (equivalent to
// descending-order greedy NMS for distinct scores), then loss = sum/cnt.
__global__ void __launch_bounds__(NT) nms_kernel(const float4* __restrict__ boxes,
                                                 const float* __restrict__ keys,
                                                 float* __restrict__ loss) {
    __shared__ float skey[NN];          // 32 KB
    __shared__ float redV[NT / 64];
    __shared__ int   redI[NT / 64];
    __shared__ float bcV;
    __shared__ int   bcI;
    const int b = blockIdx.x;
    const int tid = threadIdx.x;
    const float4* bx = boxes + (size_t)b * NN;

    for (int n = tid; n < NN; n += NT) skey[n] = keys[(size_t)b * NN + n];
    __syncthreads();

    float sum = 0.f;
    int cnt = 0;                         // only thread 0's copy is meaningful
    while (true) {
        // --- block argmax over skey ---
        float bv = -INFINITY; int bi = -1;
        for (int n = tid; n < NN; n += NT) {
            float v = skey[n];
            if (v > bv) { bv = v; bi = n; }
        }
        for (int off = 32; off; off >>= 1) {
            float ov = __shfl_xor(bv, off);
            int   oi = __shfl_xor(bi, off);
            if (ov > bv) { bv = ov; bi = oi; }
        }
        if ((tid & 63) == 0) { redV[tid >> 6] = bv; redI[tid >> 6] = bi; }
        __syncthreads();
        if (tid == 0) {
            float v0 = redV[0]; int i0 = redI[0];
            for (int w = 1; w < NT / 64; ++w)
                if (redV[w] > v0) { v0 = redV[w]; i0 = redI[w]; }
            bcV = v0; bcI = i0;
        }
        __syncthreads();
        float curV = bcV; int curI = bcI;
        if (curV == -INFINITY) break;    // uniform exit

        if (tid == 0) {
            sum += curV; cnt += 1;
            skey[curI] = -INFINITY;      // progress guarantee (benign race: only -inf written)
        }
        float4 cb = bx[curI];            // broadcast load
        float carea = (cb.z - cb.x + 1.f) * (cb.w - cb.y + 1.f);

        // --- suppress pass ---
        for (int n = tid; n < NN; n += NT) {
            float v = skey[n];
            if (v == -INFINITY) continue;
            float4 q = bx[n];
            float xx1 = fmaxf(cb.x, q.x), yy1 = fmaxf(cb.y, q.y);
            float xx2 = fminf(cb.z, q.z), yy2 = fminf(cb.w, q.w);
            float iw = fmaxf(xx2 - xx1 + 1.f, 0.f);
            float ih = fmaxf(yy2 - yy1 + 1.f, 0.f);
            float inter = iw * ih;
            float qarea = (q.z - q.x + 1.f) * (q.w - q.y + 1.f);
            float iou = inter / (carea + qarea - inter + EPS_F);
            if (iou > NMS_THR) skey[n] = -INFINITY;
        }
        __syncthreads();
    }
    if (tid == 0) loss[b] = sum / (float)cnt;   // 0/0 -> NaN matches reference
}

extern "C" void kernel_launch(void* const* d_in, const int* in_sizes, int n_in,
                              void* d_out, int out_size, void* d_ws, size_t ws_size,
                              hipStream_t stream) {
    const float* outp = (const float*)d_in[0];   // (B, N, 85) f32
    const float* lab  = (const float*)d_in[1];   // (B, M, 5)  f32
    float* loss = (float*)d_out;                 // (1, B) f32

    float4* boxes = (float4*)d_ws;                                   // B*N*16 = 2 MB
    float*  keys  = (float*)((char*)d_ws + (size_t)BB * NN * sizeof(float4)); // +512 KB

    dim3 g1(BB, NN / NT);
    prep_kernel<<<g1, NT, 0, stream>>>(outp, lab, boxes, keys);
    nms_kernel<<<BB, NT, 0, stream>>>(boxes, keys, loss);
}

// Round 2
// 183.826 us; speedup vs baseline: 3.6691x; 3.6691x over previous
//
#include <hip/hip_runtime.h>
#include <math.h>

#define BB 16
#define NN 8192
#define MM 64
#define ROW 85
#define EPS_F 1e-7f

#define NT1 256          // prep block
#define NT2 1024         // nms block
#define PT  (NN / NT2)   // 8 preds per thread
#define NW  (NT2 / 64)   // 16 waves

// Kernel 1: per-prediction boxes + masked score keys.
// key = valid ? score : -inf, valid = (obj >= 0) && (max IoU vs GT >= 0.5)
__global__ void prep_kernel(const float* __restrict__ outp,
                            const float* __restrict__ lab,
                            float4* __restrict__ boxes,
                            float* __restrict__ keys) {
    __shared__ float4 gbox[MM];
    __shared__ float garea[MM];
    const int b = blockIdx.x;
    const int tid = threadIdx.x;
    if (tid < MM) {
        const float* lr = lab + ((size_t)b * MM + tid) * 5;
        float cx = lr[1], cy = lr[2], w = lr[3], h = lr[4];
        // xywh2xyxy -> clip(0,1) -> *640 (same op order as reference)
        float x1 = fminf(fmaxf(cx - w * 0.5f, 0.f), 1.f) * 640.f;
        float y1 = fminf(fmaxf(cy - h * 0.5f, 0.f), 1.f) * 640.f;
        float x2 = fminf(fmaxf(cx + w * 0.5f, 0.f), 1.f) * 640.f;
        float y2 = fminf(fmaxf(cy + h * 0.5f, 0.f), 1.f) * 640.f;
        gbox[tid] = make_float4(x1, y1, x2, y2);
        garea[tid] = (x2 - x1) * (y2 - y1);
    }
    __syncthreads();
    const int n = blockIdx.y * NT1 + tid;
    const float* row = outp + ((size_t)b * NN + n) * ROW;
    float cx = row[0], cy = row[1], w = row[2], h = row[3];
    float obj = row[4], c0 = row[5];
    float px1 = cx - w * 0.5f, py1 = cy - h * 0.5f;
    float px2 = cx + w * 0.5f, py2 = cy + h * 0.5f;
    float pa = (px2 - px1) * (py2 - py1);

    // fast path: pred n's own GT is n % 64 and almost always matches
    const int m0 = n & (MM - 1);
    bool match;
    {
        float4 g = gbox[m0];
        float iw = fmaxf(fminf(px2, g.z) - fmaxf(px1, g.x), 0.f);
        float ih = fmaxf(fminf(py2, g.w) - fmaxf(py1, g.y), 0.f);
        float inter = iw * ih;
        float iou = inter / (garea[m0] + pa - inter);   // no EPS (matches box_iou)
        match = (iou >= 0.5f);
    }
    if (!match) {
        for (int m = 0; m < MM; ++m) {
            float4 g = gbox[m];
            float iw = fmaxf(fminf(px2, g.z) - fmaxf(px1, g.x), 0.f);
            float ih = fmaxf(fminf(py2, g.w) - fmaxf(py1, g.y), 0.f);
            float inter = iw * ih;
            float iou = inter / (garea[m] + pa - inter);
            match = match || (iou >= 0.5f);
        }
    }
    bool valid = (obj >= 0.0f) && match;
    size_t bn = (size_t)b * NN + n;
    boxes[bn] = make_float4(px1, py1, px2, py2);
    keys[bn] = valid ? (c0 * obj) : -INFINITY;
}

// Kernel 2: register-resident greedy NMS, one block per image.
// Iterative max-selection == descending-order greedy NMS (distinct scores).
__global__ void __launch_bounds__(NT2) nms_kernel(const float4* __restrict__ boxes,
                                                  const float* __restrict__ keys,
                                                  float* __restrict__ loss) {
    __shared__ float pub[2][NW][8];   // [parity][wave][score, tid, x1,y1,x2,y2, area, pad]
    const int b = blockIdx.x;
    const int tid = threadIdx.x;
    const int wid = tid >> 6;
    const int lane = tid & 63;
    const size_t base = (size_t)b * NN;

    float ex1[PT], ey1[PT], ex2[PT], ey2[PT], es[PT], ea[PT];
    #pragma unroll
    for (int k = 0; k < PT; ++k) {
        int n = k * NT2 + tid;                       // coalesced
        float4 bb = boxes[base + n];
        ex1[k] = bb.x; ey1[k] = bb.y; ex2[k] = bb.z; ey2[k] = bb.w;
        es[k] = keys[base + n];
        // same expression as reference area -> bit-identical
        ea[k] = (ex2[k] - ex1[k] + 1.f) * (ey2[k] - ey1[k] + 1.f);
    }

    // initial local argmax, tracking winner box in registers (no runtime reg index)
    float lv = -INFINITY; int la = -1;
    float bx1 = 0.f, by1 = 0.f, bx2 = 0.f, by2 = 0.f, bba = 0.f;
    #pragma unroll
    for (int k = 0; k < PT; ++k) {
        if (es[k] > lv) { lv = es[k]; la = k;
                          bx1 = ex1[k]; by1 = ey1[k]; bx2 = ex2[k]; by2 = ey2[k]; bba = ea[k]; }
    }
    int myLa = la;

    // wave argmax (value, lane) + publish
    float rv = lv; int rl = lane;
    #pragma unroll
    for (int off = 1; off < 64; off <<= 1) {
        float ov = __shfl_xor(rv, off);
        int   ol = __shfl_xor(rl, off);
        if (ov > rv) { rv = ov; rl = ol; }
    }
    if (lane == rl) {   // unique when rv finite; all--inf case writes only score, unread fields
        pub[0][wid][0] = lv;
        pub[0][wid][1] = (float)tid;
        pub[0][wid][2] = bx1; pub[0][wid][3] = by1;
        pub[0][wid][4] = bx2; pub[0][wid][5] = by2;
        pub[0][wid][6] = bba;
    }
    __syncthreads();

    float sum = 0.f; int cnt = 0; int p = 0;
    while (true) {
        // global winner: every thread scans the NW wave entries (LDS broadcast reads)
        float gv = -INFINITY; int gw = 0;
        #pragma unroll
        for (int w = 0; w < NW; ++w) {
            float v = pub[p][w][0];
            if (v > gv) { gv = v; gw = w; }
        }
        if (gv == -INFINITY) break;    // uniform exit
        sum += gv; cnt++;
        int   gtid  = (int)pub[p][gw][1];
        float cx1   = pub[p][gw][2], cy1 = pub[p][gw][3];
        float cx2   = pub[p][gw][4], cy2 = pub[p][gw][5];
        float carea = pub[p][gw][6];
        bool winner = (tid == gtid);

        // fused: suppress vs winner + next local argmax (+box tracking)
        lv = -INFINITY; la = -1;
        #pragma unroll
        for (int k = 0; k < PT; ++k) {
            float v = es[k];
            if (v != -INFINITY) {
                if (winner && k == myLa) {
                    v = -INFINITY;                       // remove the selected box
                } else {
                    float xx1 = fmaxf(cx1, ex1[k]);
                    float yy1 = fmaxf(cy1, ey1[k]);
                    float xx2 = fminf(cx2, ex2[k]);
                    float yy2 = fminf(cy2, ey2[k]);
                    float iw = fmaxf(xx2 - xx1 + 1.f, 0.f);
                    float ih = fmaxf(yy2 - yy1 + 1.f, 0.f);
                    float inter = iw * ih;
                    // exact reference association: ((carea+qarea)-inter)+EPS
                    float iou = inter / (carea + ea[k] - inter + EPS_F);
                    if (iou > 0.5f) v = -INFINITY;
                }
                es[k] = v;
            }
            if (v > lv) { lv = v; la = k;
                          bx1 = ex1[k]; by1 = ey1[k]; bx2 = ex2[k]; by2 = ey2[k]; bba = ea[k]; }
        }
        myLa = la;

        rv = lv; rl = lane;
        #pragma unroll
        for (int off = 1; off < 64; off <<= 1) {
            float ov = __shfl_xor(rv, off);
            int   ol = __shfl_xor(rl, off);
            if (ov > rv) { rv = ov; rl = ol; }
        }
        p ^= 1;
        if (lane == rl) {
            pub[p][wid][0] = lv;
            pub[p][wid][1] = (float)tid;
            pub[p][wid][2] = bx1; pub[p][wid][3] = by1;
            pub[p][wid][4] = bx2; pub[p][wid][5] = by2;
            pub[p][wid][6] = bba;
        }
        __syncthreads();
    }
    if (tid == 0) loss[b] = sum / (float)cnt;   // 0/0 -> NaN matches reference
}

extern "C" void kernel_launch(void* const* d_in, const int* in_sizes, int n_in,
                              void* d_out, int out_size, void* d_ws, size_t ws_size,
                              hipStream_t stream) {
    const float* outp = (const float*)d_in[0];   // (B, N, 85) f32
    const float* lab  = (const float*)d_in[1];   // (B, M, 5)  f32
    float* loss = (float*)d_out;                 // (1, B) f32

    float4* boxes = (float4*)d_ws;                                   // 2 MB
    float*  keys  = (float*)((char*)d_ws + (size_t)BB * NN * sizeof(float4)); // +512 KB

    dim3 g1(BB, NN / NT1);
    prep_kernel<<<g1, NT1, 0, stream>>>(outp, lab, boxes, keys);
    nms_kernel<<<BB, NT2, 0, stream>>>(boxes, keys, loss);
}